// Round 4
// baseline (142.417 us; speedup 1.0000x reference)
//
#include <hip/hip_runtime.h>
#include <math.h>

#define DD 160
#define HH 192
#define WW 160
#define TW 32          // block tile width
#define THB 32         // block tile height (32 rows x 8 w-quads = 256 threads)
#define TD 8           // slices per block
#define HW (HH * WW)
#define NVOX (DD * HW)
#define HTW 34         // halo cols
#define HTH 34         // halo rows
#define LSTR 34        // row stride == HTW keeps staging LINEAR (bS[tid])
#define HALO (HTH * HTW)   // 1156

typedef float v2f __attribute__((ext_vector_type(2)));
typedef float v4f __attribute__((ext_vector_type(4)));

__device__ __forceinline__ v2f vrcp(v2f a) {
    v2f r;
    r.x = __builtin_amdgcn_rcpf(a.x);
    r.y = __builtin_amdgcn_rcpf(a.y);
    return r;
}

// packed atan(num/den) with a SINGLE rcp: x = min(|n|,|d|) * rcp(max(|n|,|d|)),
// odd minimax poly on [0,1], quadrant select on |n|>|d|, sign = sgn(n)^sgn(d).
// err ~1e-5 rad, averages out over the 4.9M-voxel mean.
__device__ __forceinline__ v2f atan_ratio(v2f num, v2f den) {
    v2f a = __builtin_elementwise_abs(num);
    v2f b = __builtin_elementwise_abs(den);
    v2f mn = __builtin_elementwise_min(a, b);
    v2f mx = __builtin_elementwise_max(a, b);
    v2f x = mn * vrcp(mx);
    v2f x2 = x * x;
    v2f p = __builtin_elementwise_fma(x2,
            __builtin_elementwise_fma(x2,
            __builtin_elementwise_fma(x2,
            __builtin_elementwise_fma(x2,
            __builtin_elementwise_fma(x2, (v2f)(-0.0117212f), (v2f)(0.05265332f)),
            (v2f)(-0.11643287f)), (v2f)(0.19354346f)), (v2f)(-0.33262347f)),
            (v2f)(0.99997726f));
    p *= x;
    v2f q = 1.57079632679489662f - p;
    v2f res;
    res.x = a.x > b.x ? q.x : p.x;   // res >= 0 here
    res.y = a.y > b.y ? q.y : p.y;
    unsigned sx = (__float_as_uint(num.x) ^ __float_as_uint(den.x)) & 0x80000000u;
    unsigned sy = (__float_as_uint(num.y) ^ __float_as_uint(den.y)) & 0x80000000u;
    res.x = __uint_as_float(__float_as_uint(res.x) | sx);
    res.y = __uint_as_float(__float_as_uint(res.y) | sy);
    return res;
}

struct Part { v2f Px, Py, B, C; };

// R11: 4 voxels/thread (two w-pairs), 32x32 tile. R1/R2 evidence: time is
// per-stage fixed cost (barrier + LDS round trip + exposed flow latency),
// invariant to both grid size and VALU count. Halve block-stages/voxel and
// double per-thread bytes-in-flight (flow dwordx4).
__global__ __launch_bounds__(256) void demons_ori_kernel(
    const float* __restrict__ Mv, const float* __restrict__ Sv,
    const float* __restrict__ flow, float* __restrict__ out)
{
    __shared__ float buf[2][2][HALO];   // [parity][field][h*LSTR+w]
    __shared__ float redbuf[4];

    const int tid = threadIdx.x;
    const int lane = tid & 63;
    const int wid = tid >> 6;
    const int r   = tid >> 3;          // voxel row 0..31
    const int i8  = tid & 7;           // w-quad index 0..7
    const int tw4 = 4 * i8;            // block-local first col of quad
    const int w0 = blockIdx.x * TW;
    const int h0 = blockIdx.y * THB;
    const int d0 = blockIdx.z * TD;

    // slice-invariant staging slots: tid + 256*s, s=0..3, +s=4 for tid<132
    const bool has4 = (tid < HALO - 1024);   // tids 0..131
    int gb[5]; bool ok[5];
    #pragma unroll
    for (int s = 0; s < 5; ++s) {
        int i = tid + 256 * s;
        int hh = i / HTW, ww = i - HTW * hh;
        int gh = h0 + hh - 1, gw = w0 + ww - 1;
        bool act = (s < 4) || has4;
        ok[s] = act && (gh >= 0) && (gh < HH) && (gw >= 0) && (gw < WW);
        gb[s] = gh * WW + gw;
    }

    // distance-1 prefetch regs (constant-indexed, fully unrolled -> VGPRs)
    float hS[5], hM[5];

    auto issue = [&](int d) {
        const bool din = ((unsigned)d < (unsigned)DD);
        const size_t base = (size_t)d * HW;
        #pragma unroll
        for (int s = 0; s < 5; ++s) {
            bool o = din && ok[s];
            hS[s] = o ? Sv[base + gb[s]] : 0.f;
            hM[s] = o ? Mv[base + gb[s]] : 0.f;
        }
    };
    auto commit = [&](int d) {
        float* __restrict__ bS = &buf[d & 1][0][0];
        float* __restrict__ bM = &buf[d & 1][1][0];
        #pragma unroll
        for (int s = 0; s < 4; ++s) {
            bS[tid + 256 * s] = hS[s];
            bM[tid + 256 * s] = hM[s];
        }
        if (has4) { bS[tid + 1024] = hS[4]; bM[tid + 1024] = hM[4]; }
    };

    // stencil window: halo rows r..r+2, halo cols tw4..tw4+5
    // (three 8B-aligned v2f per row; pairs share the middle v2f)
    const int rb = r * LSTR + tw4;
    auto fieldPartials = [&](const float* __restrict__ b, Part& A, Part& B) {
        const float* p0 = b + rb;
        const float* p1 = p0 + LSTR;
        const float* p2 = p1 + LSTR;
        v2f a0 = *(const v2f*)p0, b0 = *(const v2f*)(p0 + 2), c0 = *(const v2f*)(p0 + 4);
        v2f a1 = *(const v2f*)p1, b1 = *(const v2f*)(p1 + 2), c1 = *(const v2f*)(p1 + 4);
        v2f a2 = *(const v2f*)p2, b2 = *(const v2f*)(p2 + 2), c2 = *(const v2f*)(p2 + 4);
        // pair A: window (a,b);  pair B: window (b,c)
        {
            v2f X0 = b0 - a0, X1 = b1 - a1, X2 = b2 - a2;
            v2f m0 = (v2f){a0.y, b0.x};
            v2f m1 = (v2f){a1.y, b1.x};
            v2f m2 = (v2f){a2.y, b2.x};
            v2f s0 = a0 + b0, s1 = a1 + b1, s2 = a2 + b2;
            v2f W0 = __builtin_elementwise_fma(m0, (v2f)(2.f), s0);
            v2f W2 = __builtin_elementwise_fma(m2, (v2f)(2.f), s2);
            v2f I0 = s0 + m0, I1 = s1 + m1, I2 = s2 + m2;
            A.Px = __builtin_elementwise_fma(X1, (v2f)(2.f), X0) + X2;
            A.Py = W2 - W0;
            A.B  = __builtin_elementwise_fma(I1, (v2f)(2.f), I0) + I2;
            A.C  = m1;
        }
        {
            v2f X0 = c0 - b0, X1 = c1 - b1, X2 = c2 - b2;
            v2f m0 = (v2f){b0.y, c0.x};
            v2f m1 = (v2f){b1.y, c1.x};
            v2f m2 = (v2f){b2.y, c2.x};
            v2f s0 = b0 + c0, s1 = b1 + c1, s2 = b2 + c2;
            v2f W0 = __builtin_elementwise_fma(m0, (v2f)(2.f), s0);
            v2f W2 = __builtin_elementwise_fma(m2, (v2f)(2.f), s2);
            v2f I0 = s0 + m0, I1 = s1 + m1, I2 = s2 + m2;
            B.Px = __builtin_elementwise_fma(X1, (v2f)(2.f), X0) + X2;
            B.Py = W2 - W0;
            B.B  = __builtin_elementwise_fma(I1, (v2f)(2.f), I0) + I2;
            B.C  = m1;
        }
    };

    // per-pair demons term
    auto pairTerm = [&](const Part& mSk, const Part& zSk, const Part& pSk,
                        const Part& mMk, const Part& zMk, const Part& pMk,
                        v2f fx, v2f fy, v2f fz) -> v2f {
        v2f idf = zMk.C - zSk.C;
        v2f i2  = __builtin_elementwise_fma(idf, idf, (v2f)(1e-10f));
        v2f gxS = mSk.Px + zSk.Px + pSk.Px;
        v2f gyS = mSk.Py + zSk.Py + pSk.Py;
        v2f gzS = pSk.B - mSk.B;
        v2f gxM = mMk.Px + zMk.Px + pMk.Px;
        v2f gyM = mMk.Py + zMk.Py + pMk.Py;
        v2f gzM = pMk.B - mMk.B;
        v2f denS = __builtin_elementwise_fma(gxS, gxS,
                   __builtin_elementwise_fma(gyS, gyS,
                   __builtin_elementwise_fma(gzS, gzS, i2)));
        v2f denM = __builtin_elementwise_fma(gxM, gxM,
                   __builtin_elementwise_fma(gyM, gyM,
                   __builtin_elementwise_fma(gzM, gzM, i2)));
        v2f rS = vrcp(denS);
        v2f rM = vrcp(denM);
        v2f Ux = idf * __builtin_elementwise_fma(gxS, rS, gxM * rM);
        v2f Uy = idf * __builtin_elementwise_fma(gyS, rS, gyM * rM);
        v2f Uz = idf * __builtin_elementwise_fma(gzS, rS, gzM * rM);
        v2f uzp = Uz + 1e-10f;
        v2f dxz = atan_ratio(Ux, uzp);
        v2f dyz = atan_ratio(Uy, uzp);
        v2f fzp = fz + 1e-10f;
        v2f fxz = atan_ratio(fx, fzp);
        v2f fyz = atan_ratio(fy, fzp);
        v2f e1 = fxz - dxz;
        v2f e2 = fyz - dyz;
        return __builtin_elementwise_fma(e1, e1, e2 * e2);
    };

    // register ring: [pair] x slice {m,z,p} x field {S,M}
    Part mS[2], zS[2], pP[2], mM[2], zM[2], pQ[2];

    // ---- warmup ----
    issue(d0 - 1);
    commit(d0 - 1);          // only long exposed vmcnt wait of the block
    issue(d0);
    __syncthreads();
    fieldPartials(&buf[(d0 - 1) & 1][0][0], mS[0], mS[1]);
    fieldPartials(&buf[(d0 - 1) & 1][1][0], mM[0], mM[1]);
    commit(d0);
    issue(d0 + 1);
    __syncthreads();
    fieldPartials(&buf[d0 & 1][0][0], zS[0], zS[1]);
    fieldPartials(&buf[d0 & 1][1][0], zM[0], zM[1]);

    const size_t voffA = (size_t)(h0 + r) * WW + (w0 + tw4);  // quad contiguous, 16B aligned
    v4f fFx, fFy, fFz;
    {
        size_t o = (size_t)d0 * HW + voffA;
        fFx = *(const v4f*)(flow + o);
        fFy = *(const v4f*)(flow + NVOX + o);
        fFz = *(const v4f*)(flow + 2 * (size_t)NVOX + o);
    }

    v2f vsum = (v2f){0.f, 0.f};

    #pragma unroll
    for (int dd = 0; dd < TD; ++dd) {
        const int d = d0 + dd;
        commit(d + 1);       // vmcnt wait for loads issued one stage ago
        v4f nFx = (v4f){0.f, 0.f, 0.f, 0.f}, nFy = nFx, nFz = nFx;
        if (dd < TD - 1) {
            issue(d + 2);    // in flight across this whole stage
            size_t o = (size_t)(d + 1) * HW + voffA;
            nFx = *(const v4f*)(flow + o);
            nFy = *(const v4f*)(flow + NVOX + o);
            nFz = *(const v4f*)(flow + 2 * (size_t)NVOX + o);
        }
        __syncthreads();
        fieldPartials(&buf[(d + 1) & 1][0][0], pP[0], pP[1]);
        fieldPartials(&buf[(d + 1) & 1][1][0], pQ[0], pQ[1]);

        vsum += pairTerm(mS[0], zS[0], pP[0], mM[0], zM[0], pQ[0],
                         (v2f){fFx.x, fFx.y}, (v2f){fFy.x, fFy.y}, (v2f){fFz.x, fFz.y});
        vsum += pairTerm(mS[1], zS[1], pP[1], mM[1], zM[1], pQ[1],
                         (v2f){fFx.z, fFx.w}, (v2f){fFy.z, fFy.w}, (v2f){fFz.z, fFz.w});

        // rotate ring (constant indices, renamed by full unroll)
        #pragma unroll
        for (int k = 0; k < 2; ++k) {
            mS[k] = zS[k]; zS[k] = pP[k];
            mM[k] = zM[k]; zM[k] = pQ[k];
        }
        fFx = nFx; fFy = nFy; fFz = nFz;
    }

    float lsum = vsum.x + vsum.y;
    // wave shuffle reduce -> per-wave LDS slot -> one atomic per block
    #pragma unroll
    for (int o = 32; o > 0; o >>= 1)
        lsum += __shfl_down(lsum, o, 64);
    if (lane == 0)
        redbuf[wid] = lsum;
    __syncthreads();
    if (tid == 0) {
        float s = redbuf[0] + redbuf[1] + redbuf[2] + redbuf[3];
        atomicAdd(out, s * (1.0f / (float)NVOX));
    }
}

extern "C" void kernel_launch(void* const* d_in, const int* in_sizes, int n_in,
                              void* d_out, int out_size, void* d_ws, size_t ws_size,
                              hipStream_t stream) {
    const float* Mv   = (const float*)d_in[0];
    const float* Sv   = (const float*)d_in[1];
    const float* flow = (const float*)d_in[2];
    float* out = (float*)d_out;

    hipMemsetAsync(out, 0, sizeof(float), stream);

    dim3 grid(WW / TW, HH / THB, DD / TD);   // 5 x 6 x 20 = 600 blocks
    demons_ori_kernel<<<grid, dim3(256), 0, stream>>>(Mv, Sv, flow, out);
}